// Round 2
// baseline (585.742 us; speedup 1.0000x reference)
//
#include <hip/hip_runtime.h>
#include <math.h>

#define NDRUG 846
#define DIM   256
#define KN    128

typedef _Float16 half8 __attribute__((ext_vector_type(8)));
typedef float f32x4 __attribute__((ext_vector_type(4)));

// ---------------- kernel 1: b2sum[k] = sum_e b2[k][e] ----------------
__global__ __launch_bounds__(256) void b2sum_kernel(const float* __restrict__ b2,
                                                    float* __restrict__ b2sum) {
    int row  = blockIdx.x * 4 + (threadIdx.x >> 6);
    int lane = threadIdx.x & 63;
    if (row >= KN) return;
    float4 v = *((const float4*)(b2 + (size_t)row * DIM) + lane);
    float s = v.x + v.y + v.z + v.w;
    #pragma unroll
    for (int off = 32; off >= 1; off >>= 1) s += __shfl_xor(s, off);
    if (lane == 0) b2sum[row] = s;
}

// ---------------- kernel 2: per-drug fused GNN (MFMA f16) ----------------
// h^T[e][k] = sum_d W1[d][e] * A[k][d],  A[k][d] = drug[d]*rela[r_k][d]
// score[k]  = b2sum[k] + sum_e relu(h^T[e][k] + b1[k][e]) * w2sum[e]
// w2sum[e]  = sum_e2 W2[n][e][e2]  -- fused as a second deep-prefetched
// global stream (2 rows/wave/step, shfl-reduced into s_w2; row schedule
// exactly matches epilogue consumption order).
// A-matrix staged ONCE for all 8 d-steps (64 KB LDS); W1/W2 registers are
// prefetched 4 steps ahead; the raw lgkmcnt-only barrier never drains vmcnt,
// so ~40 loads/thread stay in flight across steps.
__global__ __launch_bounds__(256, 2) void gnn_main(
    const int* __restrict__ adj_rel,
    const float* __restrict__ drug_table, const float* __restrict__ rela_table,
    const float* __restrict__ W1, const float* __restrict__ b1,
    const float* __restrict__ W2, const float* __restrict__ b2sum,
    float* __restrict__ score_out)
{
    __shared__ __align__(16) half8 sB[8][8][64];        // 64 KB: [dstep][kt][slot]
    __shared__ __align__(16) _Float16 sA[2][4][520];    // 8.3 KB, dbuf W1 frags
    __shared__ float s_w2[DIM];
    __shared__ float s_scoreP[4][KN];
    __shared__ float s_red[8];

    const int n    = blockIdx.x;
    const int t    = threadIdx.x;
    const int wv   = t >> 6;
    const int lane = t & 63;

    const float* W1n   = W1 + (size_t)n * DIM * DIM;
    const float* W2n   = W2 + (size_t)n * DIM * DIM;
    const float* wbase = W1n + (size_t)(wv << 3) * DIM + lane;
    const int w2row0 = (wv << 1) + (lane >> 5);   // 2 W2 rows per wave per step
    const int w2c    = lane & 31;

    // ---- tiny loads first (their waits must not drain the prefetch queue) ----
    const int kk = t >> 1, o0 = (t & 1) << 1;
    const int   rid     = adj_rel[(size_t)n * KN + kk];
    const float sc_init = b2sum[t & (KN - 1)];

    // ---- W1 + W2 prefetch, depth 4 (pure-global, no LDS dep) ----
    // step ss: W1 rows (ss&7)*32 + wv*8 + j, col (ss>>3)*64 + lane
    //          W2 rows ss*8 + wv*2 + (lane>>5), cols split 0-127 / 128-255
    float P[4][8]; float4 Qa[4], Qb[4];
    #pragma unroll
    for (int s = 0; s < 4; ++s) {
        const float* p = wbase + (size_t)((s & 7) << 5) * DIM + ((s >> 3) << 6);
        #pragma unroll
        for (int j = 0; j < 8; ++j) P[s][j] = p[(size_t)j * DIM];
        const float4* wr = (const float4*)(W2n + (size_t)((s << 3) + w2row0) * DIM);
        Qa[s] = wr[w2c]; Qb[s] = wr[32 + w2c];
    }

    // ---- A prestage: all 8 d-steps into sB, straight from global ----
    // (rela rows are L2-resident, drug row is L1-resident; no __syncthreads
    // needed before this -- first consumer sync is step 0's barrier.)
    {
        const float* rrow = rela_table + (size_t)rid * DIM;
        const float* drow = drug_table + (size_t)n * DIM;
        #pragma unroll 2
        for (int s8 = 0; s8 < 8; ++s8) {
            #pragma unroll
            for (int i = 0; i < 2; ++i) {
                const int o  = o0 | i;
                const int db = (s8 << 5) + (o << 3);
                float4 p0 = *(const float4*)(rrow + db);
                float4 p1 = *(const float4*)(rrow + db + 4);
                float4 q0 = *(const float4*)(drow + db);
                float4 q1 = *(const float4*)(drow + db + 4);
                half8 h;
                h[0] = (_Float16)(p0.x * q0.x);
                h[1] = (_Float16)(p0.y * q0.y);
                h[2] = (_Float16)(p0.z * q0.z);
                h[3] = (_Float16)(p0.w * q0.w);
                h[4] = (_Float16)(p1.x * q1.x);
                h[5] = (_Float16)(p1.y * q1.y);
                h[6] = (_Float16)(p1.z * q1.z);
                h[7] = (_Float16)(p1.w * q1.w);
                sB[s8][kk >> 4][(kk & 15) | (o << 4)] = h;   // one b128 store
            }
        }
    }

    const int kcol = lane & 15, quad = lane >> 4;
    f32x4 acc[8] = {};
    float sacc[8] = {0.f,0.f,0.f,0.f,0.f,0.f,0.f,0.f};
    const f32x4 fzero = {};

    // 32 flattened steps: ss = c*8 + s (c = e-chunk, s = d-step). Full unroll
    // so all prefetch-buffer indices are compile-time constants.
    #pragma unroll
    for (int ss = 0; ss < 32; ++ss) {
        const int rb = ss & 3;
        // 1) convert + single b128 LDS write (counted vmcnt wait on P only)
        half8 hw;
        #pragma unroll
        for (int j = 0; j < 8; ++j) hw[j] = (_Float16)P[rb][j];
        *(half8*)&sA[ss & 1][lane >> 4][((lane & 15) | (wv << 4)) << 3] = hw;
        // 2) W2 row-sum for this step (rows ss*8 .. ss*8+7 across 4 waves)
        {
            float4 qa = Qa[rb], qb = Qb[rb];
            float wsum = (qa.x + qa.y + qa.z + qa.w) + (qb.x + qb.y + qb.z + qb.w);
            wsum += __shfl_xor(wsum, 1);
            wsum += __shfl_xor(wsum, 2);
            wsum += __shfl_xor(wsum, 4);
            wsum += __shfl_xor(wsum, 8);
            wsum += __shfl_xor(wsum, 16);
            if ((lane & 31) == 0) s_w2[(ss << 3) + w2row0] = wsum;
        }
        // 3) issue prefetch for step ss+4 into the freed register slots
        if (ss + 4 < 32) {
            const int sn = ss + 4;
            const float* p = wbase + (size_t)((sn & 7) << 5) * DIM + ((sn >> 3) << 6);
            #pragma unroll
            for (int j = 0; j < 8; ++j) P[rb][j] = p[(size_t)j * DIM];
            const float4* wr = (const float4*)(W2n + (size_t)((sn << 3) + w2row0) * DIM);
            Qa[rb] = wr[w2c]; Qb[rb] = wr[32 + w2c];
        }
        // 4) LDS-only drain + raw barrier: does NOT drain vmcnt, so all
        // prefetched W1/W2 loads stay in flight across the barrier.
        asm volatile("s_waitcnt lgkmcnt(0)\n\ts_barrier" ::: "memory");
        // 5) fragments + MFMA
        half8 af = *(const half8*)&sA[ss & 1][wv][(size_t)lane << 3];
        const int ds = ss & 7;
        #pragma unroll
        for (int kt = 0; kt < 8; ++kt) {
            half8 bf = sB[ds][kt][lane];
            acc[kt] = __builtin_amdgcn_mfma_f32_16x16x32_f16(af, bf, acc[kt], 0, 0, 0);
        }
        // chunk epilogue: bias + relu + dot with w2sum (s_w2 rows < 64*(c+1)
        // were all written before this step's barrier -> visible)
        if (ds == 7) {
            const int c = ss >> 3;
            const int ebase = (c << 6) + (wv << 4) + (quad << 2);
            float4 ww = *(const float4*)(s_w2 + ebase);
            #pragma unroll
            for (int kt = 0; kt < 8; ++kt) {
                const int k = (kt << 4) + kcol;
                float4 bb = *(const float4*)(b1 + (size_t)k * DIM + ebase);
                f32x4 a = acc[kt];
                sacc[kt] += fmaxf(a[0] + bb.x, 0.f) * ww.x
                          + fmaxf(a[1] + bb.y, 0.f) * ww.y
                          + fmaxf(a[2] + bb.z, 0.f) * ww.z
                          + fmaxf(a[3] + bb.w, 0.f) * ww.w;
                acc[kt] = fzero;
            }
        }
    }

    // score reduce: quad groups hold partials for same k
    #pragma unroll
    for (int kt = 0; kt < 8; ++kt) {
        float v = sacc[kt];
        v += __shfl_xor(v, 16);
        v += __shfl_xor(v, 32);
        if (lane < 16) s_scoreP[wv][(kt << 4) + lane] = v;
    }
    __syncthreads();
    float sc = -3.0e38f;
    if (t < KN)
        sc = sc_init + (s_scoreP[0][t] + s_scoreP[1][t]) + (s_scoreP[2][t] + s_scoreP[3][t]);

    // ---- softmax over 128 neighbors ----
    float mx = sc;
    #pragma unroll
    for (int off = 32; off >= 1; off >>= 1) mx = fmaxf(mx, __shfl_xor(mx, off));
    if (lane == 0) s_red[wv] = mx;
    __syncthreads();
    float M = fmaxf(fmaxf(s_red[0], s_red[1]), fmaxf(s_red[2], s_red[3]));
    float ex = (t < KN) ? expf(sc - M) : 0.f;
    float ssum = ex;
    #pragma unroll
    for (int off = 32; off >= 1; off >>= 1) ssum += __shfl_xor(ssum, off);
    if (lane == 0) s_red[4 + wv] = ssum;
    __syncthreads();
    float S = (s_red[4] + s_red[5]) + (s_red[6] + s_red[7]);
    if (t < KN) score_out[(size_t)n * KN + t] = ex / S;
}

// ---------------- kernel 2b: weighted entity gather + concat ----------------
// drug_e[n] = [ sum_k p[k]*ent[tail_k] | drug_emb[n] ]; 8 loads in flight/thread.
__global__ __launch_bounds__(256) void gather_kernel(
    const float* __restrict__ score, const int* __restrict__ adj_tail,
    const float* __restrict__ ent_table, const float* __restrict__ drug_table,
    float* __restrict__ drug_e)
{
    __shared__ float s_p[KN];
    __shared__ int   s_ti[KN];
    const int n = blockIdx.x, t = threadIdx.x;
    if (t < KN) {
        s_p[t]  = score[(size_t)n * KN + t];
        s_ti[t] = adj_tail[(size_t)n * KN + t];
    }
    __syncthreads();
    float a0=0.f,a1=0.f,a2=0.f,a3=0.f,a4=0.f,a5=0.f,a6=0.f,a7=0.f;
    for (int k = 0; k < KN; k += 8) {
        float v0 = ent_table[(size_t)s_ti[k + 0] * DIM + t];
        float v1 = ent_table[(size_t)s_ti[k + 1] * DIM + t];
        float v2 = ent_table[(size_t)s_ti[k + 2] * DIM + t];
        float v3 = ent_table[(size_t)s_ti[k + 3] * DIM + t];
        float v4 = ent_table[(size_t)s_ti[k + 4] * DIM + t];
        float v5 = ent_table[(size_t)s_ti[k + 5] * DIM + t];
        float v6 = ent_table[(size_t)s_ti[k + 6] * DIM + t];
        float v7 = ent_table[(size_t)s_ti[k + 7] * DIM + t];
        a0 += s_p[k + 0] * v0;  a1 += s_p[k + 1] * v1;
        a2 += s_p[k + 2] * v2;  a3 += s_p[k + 3] * v3;
        a4 += s_p[k + 4] * v4;  a5 += s_p[k + 5] * v5;
        a6 += s_p[k + 6] * v6;  a7 += s_p[k + 7] * v7;
    }
    drug_e[(size_t)n * 512 + t]       = ((a0 + a1) + (a2 + a3)) + ((a4 + a5) + (a6 + a7));
    drug_e[(size_t)n * 512 + DIM + t] = drug_table[(size_t)n * DIM + t];
}

// ---------------- kernel 3: Linear(512->256) + relu + BN partial sums ----------------
__global__ __launch_bounds__(256) void linear_kernel(
    const float* __restrict__ drug_e, const float* __restrict__ lin_w,
    const float* __restrict__ lin_b,
    float* __restrict__ x, float* __restrict__ g_sum, float* __restrict__ g_sumsq)
{
    __shared__ __align__(16) float s_de[4][512];   // 8 KB
    const int b = blockIdx.x, t = threadIdx.x;
    const int n0 = b * 4;
    #pragma unroll
    for (int ss = 0; ss < 2; ++ss) {
        int idx = ss * 256 + t;
        int row = idx >> 7, col4 = idx & 127;
        float4 v = make_float4(0.f, 0.f, 0.f, 0.f);
        if (n0 + row < NDRUG) v = *((const float4*)(drug_e + (size_t)(n0 + row) * 512) + col4);
        *(float4*)&s_de[row][col4 * 4] = v;
    }
    __syncthreads();
    float acc[4] = {};
    const float4* wrow = (const float4*)(lin_w + (size_t)t * 512);  // output e = t
    #pragma unroll 4
    for (int d4 = 0; d4 < 128; ++d4) {
        float4 w = wrow[d4];
        #pragma unroll
        for (int i = 0; i < 4; ++i) {
            float4 de = *(const float4*)&s_de[i][d4 * 4];   // broadcast, conflict-free
            acc[i] += w.x * de.x + w.y * de.y + w.z * de.z + w.w * de.w;
        }
    }
    float bias = lin_b[t];
    float psum = 0.f, psq = 0.f;
    #pragma unroll
    for (int i = 0; i < 4; ++i) {
        if (n0 + i < NDRUG) {
            float v = fmaxf(acc[i] + bias, 0.f);
            x[(size_t)(n0 + i) * DIM + t] = v;
            psum += v; psq += v * v;
        }
    }
    atomicAdd(&g_sum[t], psum);
    atomicAdd(&g_sumsq[t], psq);
}

// ---------------- kernel 4: BatchNorm normalize (biased var) ----------------
__global__ __launch_bounds__(256) void bn_kernel(
    const float* __restrict__ x, const float* __restrict__ g_sum,
    const float* __restrict__ g_sumsq,
    const float* __restrict__ gamma, const float* __restrict__ beta,
    float* __restrict__ out)
{
    const int n = blockIdx.x, e = threadIdx.x;
    const float inv = 1.0f / (float)NDRUG;
    float mean = g_sum[e] * inv;
    float var  = fmaxf(g_sumsq[e] * inv - mean * mean, 0.f);
    float rstd = rsqrtf(var + 1e-5f);
    float v = x[(size_t)n * DIM + e];
    out[(size_t)n * DIM + e] = gamma[e] * (v - mean) * rstd + beta[e];
}

extern "C" void kernel_launch(void* const* d_in, const int* in_sizes, int n_in,
                              void* d_out, int out_size, void* d_ws, size_t ws_size,
                              hipStream_t stream) {
    // drug_name (d_in[0]) is arange(846) by construction — identity gather, unused.
    const int*   adj_tail   = (const int*)d_in[1];
    const int*   adj_rel    = (const int*)d_in[2];
    const float* drug_table = (const float*)d_in[3];
    const float* rela_table = (const float*)d_in[4];
    const float* ent_table  = (const float*)d_in[5];
    const float* W1         = (const float*)d_in[6];
    const float* b1         = (const float*)d_in[7];
    const float* W2         = (const float*)d_in[8];
    const float* b2         = (const float*)d_in[9];
    const float* lin_w      = (const float*)d_in[10];
    const float* lin_b      = (const float*)d_in[11];
    const float* gamma      = (const float*)d_in[12];
    const float* beta       = (const float*)d_in[13];
    float* out = (float*)d_out;

    // workspace (floats):
    // b2sum[128] | drug_e[846*512] | xbuf[846*256] | g_sum[256] | g_sumsq[256]
    // temporal alias: score_ws (846*128) overlays xbuf (dead before linear writes).
    float* ws      = (float*)d_ws;
    float* b2sum   = ws;
    float* drug_e  = ws + 128;
    float* xbuf    = drug_e + (size_t)NDRUG * 512;
    float* score_w = xbuf;                            // alias, gather-lifetime only
    float* g_sum   = xbuf + (size_t)NDRUG * DIM;
    float* g_sumsq = g_sum + DIM;

    hipMemsetAsync(g_sum, 0, 2 * DIM * sizeof(float), stream);
    b2sum_kernel<<<KN / 4, 256, 0, stream>>>(b2, b2sum);
    gnn_main<<<NDRUG, 256, 0, stream>>>(adj_rel, drug_table, rela_table,
                                        W1, b1, W2, b2sum, score_w);
    gather_kernel<<<NDRUG, 256, 0, stream>>>(score_w, adj_tail, ent_table,
                                             drug_table, drug_e);
    linear_kernel<<<(NDRUG + 3) / 4, 256, 0, stream>>>(drug_e, lin_w, lin_b,
                                                       xbuf, g_sum, g_sumsq);
    bn_kernel<<<NDRUG, 256, 0, stream>>>(xbuf, g_sum, g_sumsq, gamma, beta, out);
}

// Round 3
// 577.571 us; speedup vs baseline: 1.0141x; 1.0141x over previous
//
#include <hip/hip_runtime.h>
#include <math.h>

#define NDRUG 846
#define DIM   256
#define KN    128

typedef _Float16 half8 __attribute__((ext_vector_type(8)));
typedef _Float16 half4 __attribute__((ext_vector_type(4)));
typedef float f32x4 __attribute__((ext_vector_type(4)));

// ---------------- kernel 1: b2sum[k] = sum_e b2[k][e] ----------------
__global__ __launch_bounds__(256) void b2sum_kernel(const float* __restrict__ b2,
                                                    float* __restrict__ b2sum) {
    int row  = blockIdx.x * 4 + (threadIdx.x >> 6);
    int lane = threadIdx.x & 63;
    if (row >= KN) return;
    float4 v = *((const float4*)(b2 + (size_t)row * DIM) + lane);
    float s = v.x + v.y + v.z + v.w;
    #pragma unroll
    for (int off = 32; off >= 1; off >>= 1) s += __shfl_xor(s, off);
    if (lane == 0) b2sum[row] = s;
}

// ---------------- kernel 2: per-drug fused GNN (MFMA f16) ----------------
// h^T[e][k] = sum_d W1[d][e] * A[k][d],  A[k][d] = drug[d]*rela[r_k][d]
// score[k]  = b2sum[k] + sum_e relu(h^T[e][k] + b1[k][e]) * w2sum[e]
// DRAM-efficiency restructure: 8 pure d-steps; each step streams the FULL
// 32x256 W1 panel (contiguous 1-KB rows per load instr) and 32 full W2 rows.
// All 4 e-chunks' accumulators stay resident (acc[4][8], 128 VGPRs).
// W1 f32->f16 transpose done in-register (thread holds 8d x 4e block),
// written to LDS with XOR d-quad swizzle: f16 slot = e*32 + (dq ^ ((e>>2)&7))*4.
// sB (drug*rela) restaged per step, double-buffered. Raw lgkmcnt-only
// barrier keeps next-step global loads in flight across steps.
__global__ __launch_bounds__(256, 2) void gnn_main(
    const int* __restrict__ adj_rel,
    const float* __restrict__ drug_table, const float* __restrict__ rela_table,
    const float* __restrict__ W1, const float* __restrict__ b1,
    const float* __restrict__ W2, const float* __restrict__ b2sum,
    float* __restrict__ score_out)
{
    __shared__ __align__(16) _Float16 sA[2][256 * 32];  // 32 KB, d-swizzled W1^T
    __shared__ __align__(16) half8 sB[2][8][64];        // 16 KB, dbuf A-matrix
    __shared__ float s_w2[DIM];
    __shared__ float s_scoreP[4][KN];
    __shared__ float s_red[8];

    const int n    = blockIdx.x;
    const int t    = threadIdx.x;
    const int wv   = t >> 6;
    const int lane = t & 63;

    const float* W1n = W1 + (size_t)n * DIM * DIM;
    const float* W2n = W2 + (size_t)n * DIM * DIM;
    // W1: instruction k reads row (s*32 + wv*8 + k) fully: 64 lanes x 16 B = 1 KB
    const float4* w1base = (const float4*)W1n + (size_t)(wv << 3) * 64 + lane;
    // W2: 8 rows/wave/step via 4 row-pairs, halves of each 1-KB row
    const float4* w2base = (const float4*)W2n + (size_t)((wv << 3) + (lane >> 5)) * 64 + (lane & 31);

    // ---- tiny loads (must not drain the prefetch queue later) ----
    const int kk = t >> 1, o0 = (t & 1) << 1;
    const int   rid     = adj_rel[(size_t)n * KN + kk];
    const float sc_init = b2sum[t & (KN - 1)];
    const float4* rrow = (const float4*)(rela_table + (size_t)rid * DIM);
    const float4* drow = (const float4*)(drug_table + (size_t)n * DIM);

    // ---- prologue: issue step-0 W1 + W2 loads ----
    float4 P[8]; float4 Qa[4], Qb[4];
    #pragma unroll
    for (int k = 0; k < 8; ++k) P[k] = w1base[k * 64];
    #pragma unroll
    for (int p = 0; p < 4; ++p) { Qa[p] = w2base[p * 128]; Qb[p] = w2base[p * 128 + 32]; }

    const int kE   = lane & 7;          // write-side XOR key (d-quad units)
    const int kcol = lane & 15, quad = lane >> 4;
    f32x4 acc[4][8] = {};

    #pragma unroll 2
    for (int s = 0; s < 8; ++s) {
        const int buf = s & 1;
        // --- 1) W1 transpose-write: 8 x half4, 8-B aligned, XOR-swizzled ---
        #pragma unroll
        for (int i = 0; i < 4; ++i) {
            const int e = (lane << 2) + i;
            #pragma unroll
            for (int h = 0; h < 2; ++h) {
                half4 v;
                v[0] = (_Float16)((&P[4 * h + 0].x)[i]);
                v[1] = (_Float16)((&P[4 * h + 1].x)[i]);
                v[2] = (_Float16)((&P[4 * h + 2].x)[i]);
                v[3] = (_Float16)((&P[4 * h + 3].x)[i]);
                const int Q = (wv << 1) + h;            // d-quad 0..7
                *(half4*)&sA[buf][e * 32 + ((Q ^ kE) << 2)] = v;
            }
        }
        // --- 2) issue next-step W1 loads (window = rest of this step) ---
        if (s < 7) {
            #pragma unroll
            for (int k = 0; k < 8; ++k) P[k] = w1base[(s + 1) * 2048 + k * 64];
        }
        // --- 3) sB restage for d-range s*32..s*32+31 (rela L2-resident) ---
        #pragma unroll
        for (int i2 = 0; i2 < 2; ++i2) {
            const int o  = o0 | i2;
            const int f4 = (s << 3) + (o << 1);  // float4 col within row
            float4 p0 = rrow[f4], p1 = rrow[f4 + 1];
            float4 q0 = drow[f4], q1 = drow[f4 + 1];
            half8 hh;
            hh[0] = (_Float16)(p0.x * q0.x);
            hh[1] = (_Float16)(p0.y * q0.y);
            hh[2] = (_Float16)(p0.z * q0.z);
            hh[3] = (_Float16)(p0.w * q0.w);
            hh[4] = (_Float16)(p1.x * q1.x);
            hh[5] = (_Float16)(p1.y * q1.y);
            hh[6] = (_Float16)(p1.z * q1.z);
            hh[7] = (_Float16)(p1.w * q1.w);
            sB[buf][kk >> 4][(kk & 15) | (o << 4)] = hh;
        }
        // --- 4) W2 row-sums: rows s*32 + wv*8 + p*2 + (lane>>5) ---
        #pragma unroll
        for (int p = 0; p < 4; ++p) {
            float4 qa = Qa[p], qb = Qb[p];
            float w = (qa.x + qa.y + qa.z + qa.w) + (qb.x + qb.y + qb.z + qb.w);
            w += __shfl_xor(w, 1);
            w += __shfl_xor(w, 2);
            w += __shfl_xor(w, 4);
            w += __shfl_xor(w, 8);
            w += __shfl_xor(w, 16);
            if ((lane & 31) == 0)
                s_w2[(s << 5) + (wv << 3) + (p << 1) + (lane >> 5)] = w;
        }
        // --- 5) issue next-step W2 loads ---
        if (s < 7) {
            #pragma unroll
            for (int p = 0; p < 4; ++p) {
                Qa[p] = w2base[(s + 1) * 2048 + p * 128];
                Qb[p] = w2base[(s + 1) * 2048 + p * 128 + 32];
            }
        }
        // --- 6) LDS-only drain + raw barrier (vmcnt stays in flight) ---
        asm volatile("s_waitcnt lgkmcnt(0)\n\ts_barrier" ::: "memory");
        // --- 7) MFMA: 4 e-chunks x 8 k-tiles ---
        #pragma unroll
        for (int c = 0; c < 4; ++c) {
            const int e_l = ((c << 2) + wv) * 16 + kcol;
            const int kEl = (e_l >> 2) & 7;
            const int Q0  = quad << 1;
            half4 a0 = *(const half4*)&sA[buf][e_l * 32 + ((Q0 ^ kEl) << 2)];
            half4 a1 = *(const half4*)&sA[buf][e_l * 32 + (((Q0 + 1) ^ kEl) << 2)];
            half8 af;
            af[0] = a0[0]; af[1] = a0[1]; af[2] = a0[2]; af[3] = a0[3];
            af[4] = a1[0]; af[5] = a1[1]; af[6] = a1[2]; af[7] = a1[3];
            #pragma unroll
            for (int kt = 0; kt < 8; ++kt) {
                half8 bf = sB[buf][kt][lane];
                acc[c][kt] = __builtin_amdgcn_mfma_f32_16x16x32_f16(af, bf, acc[c][kt], 0, 0, 0);
            }
        }
    }

    // ---- epilogue: bias + relu + dot with w2sum (s_w2 complete) ----
    float sacc[8] = {0.f,0.f,0.f,0.f,0.f,0.f,0.f,0.f};
    #pragma unroll
    for (int c = 0; c < 4; ++c) {
        const int ebase = (c << 6) + (wv << 4) + (quad << 2);
        float4 ww = *(const float4*)(s_w2 + ebase);
        #pragma unroll
        for (int kt = 0; kt < 8; ++kt) {
            const int k = (kt << 4) + kcol;
            float4 bb = *(const float4*)(b1 + (size_t)k * DIM + ebase);
            f32x4 a = acc[c][kt];
            sacc[kt] += fmaxf(a[0] + bb.x, 0.f) * ww.x
                      + fmaxf(a[1] + bb.y, 0.f) * ww.y
                      + fmaxf(a[2] + bb.z, 0.f) * ww.z
                      + fmaxf(a[3] + bb.w, 0.f) * ww.w;
        }
    }

    // score reduce: quad groups hold partials for same k
    #pragma unroll
    for (int kt = 0; kt < 8; ++kt) {
        float v = sacc[kt];
        v += __shfl_xor(v, 16);
        v += __shfl_xor(v, 32);
        if (lane < 16) s_scoreP[wv][(kt << 4) + lane] = v;
    }
    __syncthreads();
    float sc = -3.0e38f;
    if (t < KN)
        sc = sc_init + (s_scoreP[0][t] + s_scoreP[1][t]) + (s_scoreP[2][t] + s_scoreP[3][t]);

    // ---- softmax over 128 neighbors ----
    float mx = sc;
    #pragma unroll
    for (int off = 32; off >= 1; off >>= 1) mx = fmaxf(mx, __shfl_xor(mx, off));
    if (lane == 0) s_red[wv] = mx;
    __syncthreads();
    float M = fmaxf(fmaxf(s_red[0], s_red[1]), fmaxf(s_red[2], s_red[3]));
    float ex = (t < KN) ? expf(sc - M) : 0.f;
    float ssum = ex;
    #pragma unroll
    for (int off = 32; off >= 1; off >>= 1) ssum += __shfl_xor(ssum, off);
    if (lane == 0) s_red[4 + wv] = ssum;
    __syncthreads();
    float S = (s_red[4] + s_red[5]) + (s_red[6] + s_red[7]);
    if (t < KN) score_out[(size_t)n * KN + t] = ex / S;
}

// ---------------- kernel 2b: weighted entity gather + concat ----------------
__global__ __launch_bounds__(256) void gather_kernel(
    const float* __restrict__ score, const int* __restrict__ adj_tail,
    const float* __restrict__ ent_table, const float* __restrict__ drug_table,
    float* __restrict__ drug_e)
{
    __shared__ float s_p[KN];
    __shared__ int   s_ti[KN];
    const int n = blockIdx.x, t = threadIdx.x;
    if (t < KN) {
        s_p[t]  = score[(size_t)n * KN + t];
        s_ti[t] = adj_tail[(size_t)n * KN + t];
    }
    __syncthreads();
    float a0=0.f,a1=0.f,a2=0.f,a3=0.f,a4=0.f,a5=0.f,a6=0.f,a7=0.f;
    for (int k = 0; k < KN; k += 8) {
        float v0 = ent_table[(size_t)s_ti[k + 0] * DIM + t];
        float v1 = ent_table[(size_t)s_ti[k + 1] * DIM + t];
        float v2 = ent_table[(size_t)s_ti[k + 2] * DIM + t];
        float v3 = ent_table[(size_t)s_ti[k + 3] * DIM + t];
        float v4 = ent_table[(size_t)s_ti[k + 4] * DIM + t];
        float v5 = ent_table[(size_t)s_ti[k + 5] * DIM + t];
        float v6 = ent_table[(size_t)s_ti[k + 6] * DIM + t];
        float v7 = ent_table[(size_t)s_ti[k + 7] * DIM + t];
        a0 += s_p[k + 0] * v0;  a1 += s_p[k + 1] * v1;
        a2 += s_p[k + 2] * v2;  a3 += s_p[k + 3] * v3;
        a4 += s_p[k + 4] * v4;  a5 += s_p[k + 5] * v5;
        a6 += s_p[k + 6] * v6;  a7 += s_p[k + 7] * v7;
    }
    drug_e[(size_t)n * 512 + t]       = ((a0 + a1) + (a2 + a3)) + ((a4 + a5) + (a6 + a7));
    drug_e[(size_t)n * 512 + DIM + t] = drug_table[(size_t)n * DIM + t];
}

// ---------------- kernel 3: Linear(512->256) + relu + BN partial sums ----------------
__global__ __launch_bounds__(256) void linear_kernel(
    const float* __restrict__ drug_e, const float* __restrict__ lin_w,
    const float* __restrict__ lin_b,
    float* __restrict__ x, float* __restrict__ g_sum, float* __restrict__ g_sumsq)
{
    __shared__ __align__(16) float s_de[4][512];   // 8 KB
    const int b = blockIdx.x, t = threadIdx.x;
    const int n0 = b * 4;
    #pragma unroll
    for (int ss = 0; ss < 2; ++ss) {
        int idx = ss * 256 + t;
        int row = idx >> 7, col4 = idx & 127;
        float4 v = make_float4(0.f, 0.f, 0.f, 0.f);
        if (n0 + row < NDRUG) v = *((const float4*)(drug_e + (size_t)(n0 + row) * 512) + col4);
        *(float4*)&s_de[row][col4 * 4] = v;
    }
    __syncthreads();
    float acc[4] = {};
    const float4* wrow = (const float4*)(lin_w + (size_t)t * 512);  // output e = t
    #pragma unroll 4
    for (int d4 = 0; d4 < 128; ++d4) {
        float4 w = wrow[d4];
        #pragma unroll
        for (int i = 0; i < 4; ++i) {
            float4 de = *(const float4*)&s_de[i][d4 * 4];   // broadcast, conflict-free
            acc[i] += w.x * de.x + w.y * de.y + w.z * de.z + w.w * de.w;
        }
    }
    float bias = lin_b[t];
    float psum = 0.f, psq = 0.f;
    #pragma unroll
    for (int i = 0; i < 4; ++i) {
        if (n0 + i < NDRUG) {
            float v = fmaxf(acc[i] + bias, 0.f);
            x[(size_t)(n0 + i) * DIM + t] = v;
            psum += v; psq += v * v;
        }
    }
    atomicAdd(&g_sum[t], psum);
    atomicAdd(&g_sumsq[t], psq);
}

// ---------------- kernel 4: BatchNorm normalize (biased var) ----------------
__global__ __launch_bounds__(256) void bn_kernel(
    const float* __restrict__ x, const float* __restrict__ g_sum,
    const float* __restrict__ g_sumsq,
    const float* __restrict__ gamma, const float* __restrict__ beta,
    float* __restrict__ out)
{
    const int n = blockIdx.x, e = threadIdx.x;
    const float inv = 1.0f / (float)NDRUG;
    float mean = g_sum[e] * inv;
    float var  = fmaxf(g_sumsq[e] * inv - mean * mean, 0.f);
    float rstd = rsqrtf(var + 1e-5f);
    float v = x[(size_t)n * DIM + e];
    out[(size_t)n * DIM + e] = gamma[e] * (v - mean) * rstd + beta[e];
}

extern "C" void kernel_launch(void* const* d_in, const int* in_sizes, int n_in,
                              void* d_out, int out_size, void* d_ws, size_t ws_size,
                              hipStream_t stream) {
    // drug_name (d_in[0]) is arange(846) by construction — identity gather, unused.
    const int*   adj_tail   = (const int*)d_in[1];
    const int*   adj_rel    = (const int*)d_in[2];
    const float* drug_table = (const float*)d_in[3];
    const float* rela_table = (const float*)d_in[4];
    const float* ent_table  = (const float*)d_in[5];
    const float* W1         = (const float*)d_in[6];
    const float* b1         = (const float*)d_in[7];
    const float* W2         = (const float*)d_in[8];
    const float* b2         = (const float*)d_in[9];
    const float* lin_w      = (const float*)d_in[10];
    const float* lin_b      = (const float*)d_in[11];
    const float* gamma      = (const float*)d_in[12];
    const float* beta       = (const float*)d_in[13];
    float* out = (float*)d_out;

    // workspace (floats):
    // b2sum[128] | drug_e[846*512] | xbuf[846*256] | g_sum[256] | g_sumsq[256]
    // temporal alias: score_ws (846*128) overlays xbuf (dead before linear writes).
    float* ws      = (float*)d_ws;
    float* b2sum   = ws;
    float* drug_e  = ws + 128;
    float* xbuf    = drug_e + (size_t)NDRUG * 512;
    float* score_w = xbuf;                            // alias, gather-lifetime only
    float* g_sum   = xbuf + (size_t)NDRUG * DIM;
    float* g_sumsq = g_sum + DIM;

    hipMemsetAsync(g_sum, 0, 2 * DIM * sizeof(float), stream);
    b2sum_kernel<<<KN / 4, 256, 0, stream>>>(b2, b2sum);
    gnn_main<<<NDRUG, 256, 0, stream>>>(adj_rel, drug_table, rela_table,
                                        W1, b1, W2, b2sum, score_w);
    gather_kernel<<<NDRUG, 256, 0, stream>>>(score_w, adj_tail, ent_table,
                                             drug_table, drug_e);
    linear_kernel<<<(NDRUG + 3) / 4, 256, 0, stream>>>(drug_e, lin_w, lin_b,
                                                       xbuf, g_sum, g_sumsq);
    bn_kernel<<<NDRUG, 256, 0, stream>>>(xbuf, g_sum, g_sumsq, gamma, beta, out);
}